// Round 11
// baseline (189.624 us; speedup 1.0000x reference)
//
#include <hip/hip_runtime.h>

#define BB 8
#define NN 8192
#define NPOINT 2048
#define NSAMPLE 64
#define CIN 64
#define RADIUS 0.2f
#define R2 (RADIUS * RADIUS)

// d_out layout (flat floats, reference return order)
#define OFF_NEWXYZ 0
#define OFF_FEAT (BB * NPOINT * 3)
#define OFF_INDS (OFF_FEAT + BB * NPOINT * 128)
#define OFF_IDX (OFF_INDS + BB * NPOINT)

typedef _Float16 half8 __attribute__((ext_vector_type(8)));
typedef _Float16 half4 __attribute__((ext_vector_type(4)));
typedef __fp16 f16x2 __attribute__((ext_vector_type(2)));
typedef float floatx16 __attribute__((ext_vector_type(16)));
typedef unsigned int uint2v __attribute__((ext_vector_type(2)));

// Fallback-kernel LDS strides (halves).
#define P0 88
#define P1 72
#define WT0_S 0
#define WT1_S (64 * P0)
#define WT2_S (WT1_S + 64 * P0)
#define SM_H (WT2_S + 128 * P1)   // 40960 B (fallback mlp_r)
#define XSL (64 * P0)

#define QPW 8  // fallback queries/wave

// d_ws layout (halves): fp16 features, then fp16 weight fragment tables.
// W0: 64x80 (cols 0-63 feat, 64-66 xyz, 67 bias=t0). W1: 64x80 (col 67 =
// t1 bias). W2: 128x64.
#define WSF16H (BB * NN * CIN)
#define WT0_OFF WSF16H
#define WT1_OFF (WT0_OFF + 64 * 80)
#define WT2_OFF (WT1_OFF + 64 * 80)
#define WS_END (WT2_OFF + 128 * 64)
#define WS_NEED ((size_t)WS_END * 2)

// ---------------------------------------------------------------------------
// Kernel 1 (R22): ball query with FOUR queries per wave — one point stream
// feeds four independent dot/ballot/scatter chains (R11's proven 1->2 move,
// extended). Total point-stream loads halve vs 2q/wave; per-chunk loads
// amortize over 4 chains in the latency-bound regime. Per-query hit math is
// source-identical to the R20-passing kernel. Prologue jobs unchanged:
// fp32->fp16 feature conversion (2 half8/thread now) + block-0 weight table.
// ---------------------------------------------------------------------------
__global__ __launch_bounds__(256) void ballq_kernel(
    const float* __restrict__ xyz, const int* __restrict__ inds,
    float* __restrict__ out, const float* __restrict__ features,
    _Float16* __restrict__ ws16, const float* __restrict__ w0,
    const float* __restrict__ s0, const float* __restrict__ t0,
    const float* __restrict__ w1, const float* __restrict__ s1,
    const float* __restrict__ t1, const float* __restrict__ w2,
    const float* __restrict__ s2) {
  if (ws16) {
    // feature conversion: 1024 blocks x 256 thr x 2 half8 = exact fit
    const int t0i = blockIdx.x * 256 + threadIdx.x;
    const float4* src = (const float4*)features;
#pragma unroll
    for (int i = 0; i < 2; ++i) {
      const int t = i * (BB * NN * CIN / 16) + t0i;  // 262144 stride
      const float4 a = src[2 * t + 0];
      const float4 b = src[2 * t + 1];
      union {
        half8 v;
        f16x2 p[4];
      } u;
      u.p[0] = __builtin_amdgcn_cvt_pkrtz(a.x, a.y);
      u.p[1] = __builtin_amdgcn_cvt_pkrtz(a.z, a.w);
      u.p[2] = __builtin_amdgcn_cvt_pkrtz(b.x, b.y);
      u.p[3] = __builtin_amdgcn_cvt_pkrtz(b.z, b.w);
      ((half8*)ws16)[t] = u.v;
    }
    if (blockIdx.x == 0) {
      const int tt = threadIdx.x;
      if (tt < 64) {
        const int d = tt;
        const float sd = s0[d], td = t0[d];
        _Float16* row = ws16 + WT0_OFF + d * 80;
        for (int c = 0; c < 80; ++c) {
          float v = 0.0f;
          if (c < 64) v = w0[(3 + c) * 64 + d] * sd;
          else if (c < 67) v = w0[(c - 64) * 64 + d] * sd;
          else if (c == 67) v = td;
          row[c] = (_Float16)v;
        }
      } else if (tt < 128) {
        const int d = tt - 64;
        const float sd = s1[d], td = t1[d];
        _Float16* row = ws16 + WT1_OFF + d * 80;
        for (int c = 0; c < 80; ++c) {
          float v = 0.0f;
          if (c < 64) v = w1[c * 64 + d] * sd;
          else if (c == 67) v = td;
          row[c] = (_Float16)v;
        }
      } else {
        const int d2 = tt - 128;
        const float sd = s2[d2];
        _Float16* row = ws16 + WT2_OFF + d2 * 64;
        for (int c = 0; c < 64; ++c) row[c] = (_Float16)(w2[c * 128 + d2] * sd);
      }
    }
  }

  __shared__ int sidx[4][4][NSAMPLE];  // 4 KB: 4 waves x 4 queries
  const int wave = (blockIdx.x * 256 + threadIdx.x) >> 6;
  const int lane = threadIdx.x & 63;
  const int wid = threadIdx.x >> 6;
  const int q0 = wave * 4;  // 4 queries share a batch (4 | 2048)
  const int b = q0 >> 11;

  const float* xb = xyz + (size_t)b * NN * 3;
  const int i0 = inds[q0], i1 = inds[q0 + 1], i2 = inds[q0 + 2],
            i3 = inds[q0 + 3];
  const float c0x = xb[i0 * 3 + 0], c0y = xb[i0 * 3 + 1], c0z = xb[i0 * 3 + 2];
  const float c1x = xb[i1 * 3 + 0], c1y = xb[i1 * 3 + 1], c1z = xb[i1 * 3 + 2];
  const float c2x = xb[i2 * 3 + 0], c2y = xb[i2 * 3 + 1], c2z = xb[i2 * 3 + 2];
  const float c3x = xb[i3 * 3 + 0], c3y = xb[i3 * 3 + 1], c3z = xb[i3 * 3 + 2];

  if (lane < 4) {
    const int qq_ = q0 + lane;
    const int ii = lane == 0 ? i0 : lane == 1 ? i1 : lane == 2 ? i2 : i3;
    const float sx = lane == 0 ? c0x : lane == 1 ? c1x : lane == 2 ? c2x : c3x;
    const float sy = lane == 0 ? c0y : lane == 1 ? c1y : lane == 2 ? c2y : c3y;
    const float sz = lane == 0 ? c0z : lane == 1 ? c1z : lane == 2 ? c2z : c3z;
    out[OFF_NEWXYZ + (size_t)qq_ * 3 + 0] = sx;
    out[OFF_NEWXYZ + (size_t)qq_ * 3 + 1] = sy;
    out[OFF_NEWXYZ + (size_t)qq_ * 3 + 2] = sz;
    out[OFF_INDS + qq_] = (float)ii;
  }

  const float qq0 = c0x * c0x + c0y * c0y + c0z * c0z;
  const float qq1 = c1x * c1x + c1y * c1y + c1z * c1z;
  const float qq2 = c2x * c2x + c2y * c2y + c2z * c2z;
  const float qq3 = c3x * c3x + c3y * c3y + c3z * c3z;

  int cnt0 = 0, cnt1 = 0, cnt2 = 0, cnt3 = 0;
  float ax[4], ay[4], az[4];
#pragma unroll
  for (int k = 0; k < 4; ++k) {
    const float* p = xb + (size_t)(k * 64 + lane) * 3;
    ax[k] = p[0];
    ay[k] = p[1];
    az[k] = p[2];
  }
  for (int j0 = 0; j0 < NN; j0 += 256) {
    float bx[4] = {0}, by[4] = {0}, bz[4] = {0};
    const int jn = j0 + 256;
    if (jn < NN) {  // prefetch next chunk while ballots run on current
#pragma unroll
      for (int k = 0; k < 4; ++k) {
        const float* p = xb + (size_t)(jn + k * 64 + lane) * 3;
        bx[k] = p[0];
        by[k] = p[1];
        bz[k] = p[2];
      }
    }
#pragma unroll
    for (int k = 0; k < 4; ++k) {  // k-major preserves point order
      const int j = j0 + k * 64 + lane;
      const float nn_ = ax[k] * ax[k] + ay[k] * ay[k] + az[k] * az[k];
      const float dot0 = c0x * ax[k] + c0y * ay[k] + c0z * az[k];
      const float dot1 = c1x * ax[k] + c1y * ay[k] + c1z * az[k];
      const float dot2 = c2x * ax[k] + c2y * ay[k] + c2z * az[k];
      const float dot3 = c3x * ax[k] + c3y * ay[k] + c3z * az[k];
      const bool hit0 = (qq0 + nn_ - 2.0f * dot0) < R2;
      const bool hit1 = (qq1 + nn_ - 2.0f * dot1) < R2;
      const bool hit2 = (qq2 + nn_ - 2.0f * dot2) < R2;
      const bool hit3 = (qq3 + nn_ - 2.0f * dot3) < R2;
      const unsigned long long m0 = __ballot(hit0);
      const unsigned long long m1 = __ballot(hit1);
      const unsigned long long m2 = __ballot(hit2);
      const unsigned long long m3 = __ballot(hit3);
      const unsigned long long below = (1ull << lane) - 1ull;
      if (hit0) {
        const int pos = cnt0 + (int)__popcll(m0 & below);
        if (pos < NSAMPLE) sidx[wid][0][pos] = j;
      }
      if (hit1) {
        const int pos = cnt1 + (int)__popcll(m1 & below);
        if (pos < NSAMPLE) sidx[wid][1][pos] = j;
      }
      if (hit2) {
        const int pos = cnt2 + (int)__popcll(m2 & below);
        if (pos < NSAMPLE) sidx[wid][2][pos] = j;
      }
      if (hit3) {
        const int pos = cnt3 + (int)__popcll(m3 & below);
        if (pos < NSAMPLE) sidx[wid][3][pos] = j;
      }
      cnt0 += (int)__popcll(m0);
      cnt1 += (int)__popcll(m1);
      cnt2 += (int)__popcll(m2);
      cnt3 += (int)__popcll(m3);
    }
    if (cnt0 >= NSAMPLE && cnt1 >= NSAMPLE && cnt2 >= NSAMPLE &&
        cnt3 >= NSAMPLE)
      break;
#pragma unroll
    for (int k = 0; k < 4; ++k) {
      ax[k] = bx[k];
      ay[k] = by[k];
      az[k] = bz[k];
    }
  }
  // Pad with first hit (center always hits itself -> cnt >= 1). Same-wave DS
  // ops are in-order: reads below see the scatter writes without a barrier.
  const int v0 = sidx[wid][0][lane < cnt0 ? lane : 0];
  out[OFF_IDX + (size_t)q0 * NSAMPLE + lane] = (float)v0;
  const int v1 = sidx[wid][1][lane < cnt1 ? lane : 0];
  out[OFF_IDX + (size_t)(q0 + 1) * NSAMPLE + lane] = (float)v1;
  const int v2 = sidx[wid][2][lane < cnt2 ? lane : 0];
  out[OFF_IDX + (size_t)(q0 + 2) * NSAMPLE + lane] = (float)v2;
  const int v3 = sidx[wid][3][lane < cnt3 ? lane : 0];
  out[OFF_IDX + (size_t)(q0 + 3) * NSAMPLE + lane] = (float)v3;
}

// ---- in-register layer boundary (R16/R18-verified) --------------------------
__device__ inline unsigned int pkru(float a, float b) {
  union {
    f16x2 p;
    unsigned int u;
  } t;
  t.p = __builtin_amdgcn_cvt_pkrtz(fmaxf(a, 0.0f), fmaxf(b, 0.0f));
  return t.u;
}
__device__ inline void build_frags(const floatx16& acc, half8& f0, half8& f1) {
  unsigned int P[4], Q[4];
#pragma unroll
  for (int rg = 0; rg < 4; ++rg) {
    P[rg] = pkru(acc[4 * rg + 0], acc[4 * rg + 1]);
    Q[rg] = pkru(acc[4 * rg + 2], acc[4 * rg + 3]);
  }
  union {
    unsigned int u[4];
    half8 h;
  } o;
  uint2v sp = __builtin_amdgcn_permlane32_swap(P[0], P[1], false, false);
  uint2v sq = __builtin_amdgcn_permlane32_swap(Q[0], Q[1], false, false);
  o.u[0] = sp.x; o.u[1] = sq.x; o.u[2] = sp.y; o.u[3] = sq.y;
  f0 = o.h;
  sp = __builtin_amdgcn_permlane32_swap(P[2], P[3], false, false);
  sq = __builtin_amdgcn_permlane32_swap(Q[2], Q[3], false, false);
  o.u[0] = sp.x; o.u[1] = sq.x; o.u[2] = sp.y; o.u[3] = sq.y;
  f1 = o.h;
}

// ---------------------------------------------------------------------------
// Kernel 2 (R20-proven, 57-62us): PAIRED-CHAIN zero-LDS MLP. Both queries run
// simultaneously (two independent dep chains interleave; shared weight
// fragments). Zero LDS; 8192 one-wave blocks; (64,2). UNCHANGED.
// ---------------------------------------------------------------------------
__global__ __launch_bounds__(64, 2) void mlp_p(
    const float* __restrict__ xyz, const _Float16* __restrict__ ws16,
    const int* __restrict__ inds, const float* __restrict__ t2,
    float* __restrict__ out) {
  const int l = threadIdx.x & 63;
  const int l31 = l & 31;
  const int h5 = l >> 5;
  const int koff = h5 * 8;

  // XCD swizzle: 8192 blocks = 8 XCDs x 1024; 1024 logical blocks = 1 batch.
  const int lb = (blockIdx.x & 7) * ((int)gridDim.x >> 3) + (blockIdx.x >> 3);
  const int q0 = lb * 2, q1 = q0 + 1;  // pair never straddles batch boundary
  const int b = q0 >> 11;
  const float* xb = xyz + (size_t)b * NN * 3;
  const _Float16* fb16 = ws16 + (size_t)b * NN * CIN;
  const _Float16* wt0 = ws16 + WT0_OFF;
  const _Float16* wt1q = wt0 + 64 * 80;
  const _Float16* wt2q = wt0 + 64 * 80 + 64 * 80;

  float t2v[4];
#pragma unroll
  for (int ct = 0; ct < 4; ++ct) t2v[ct] = t2[ct * 32 + l31];
  // constant K=80 bias fragment for L1 (k = 64 + 8*h5 + j; k==67 -> 1.0)
  half8 bias_f = {};
  if (h5 == 0) bias_f[3] = (_Float16)1.0f;

  // ---- prologue: BOTH queries' idx / center / pp (all issued up front) ----
  const int idxA = (int)out[OFF_IDX + (size_t)q0 * NSAMPLE + l];
  const int idxB = (int)out[OFF_IDX + (size_t)q1 * NSAMPLE + l];
  const int iA = inds[q0], iB = inds[q1];
  const float cAx = xb[iA * 3 + 0], cAy = xb[iA * 3 + 1], cAz = xb[iA * 3 + 2];
  const float cBx = xb[iB * 3 + 0], cBy = xb[iB * 3 + 1], cBz = xb[iB * 3 + 2];
  const float pAx = xb[idxA * 3 + 0], pAy = xb[idxA * 3 + 1],
              pAz = xb[idxA * 3 + 2];
  const float pBx = xb[idxB * 3 + 0], pBy = xb[idxB * 3 + 1],
              pBz = xb[idxB * 3 + 2];

  // ---- fragment-direct fp16 gathers for BOTH queries (32 loads in flight) --
  half8 xaA[2][5], xaB[2][5];
#pragma unroll
  for (int st = 0; st < 2; ++st) {
    const int sA = __shfl(idxA, st * 32 + l31, 64);
    const int sB = __shfl(idxB, st * 32 + l31, 64);
    const _Float16* baseA = fb16 + (size_t)sA * CIN + koff;
    const _Float16* baseB = fb16 + (size_t)sB * CIN + koff;
#pragma unroll
    for (int ks = 0; ks < 4; ++ks) {
      xaA[st][ks] = *(const half8*)(baseA + ks * 16);
      xaB[st][ks] = *(const half8*)(baseB + ks * 16);
    }
  }
  // xyz+bias fragments (k 64..79): h5==0 holds {dx,dy,dz,1,0..}, h5==1 zeros
#pragma unroll
  for (int st = 0; st < 2; ++st) {
    const float sxA = __shfl(pAx, st * 32 + l31, 64);
    const float syA = __shfl(pAy, st * 32 + l31, 64);
    const float szA = __shfl(pAz, st * 32 + l31, 64);
    const float sxB = __shfl(pBx, st * 32 + l31, 64);
    const float syB = __shfl(pBy, st * 32 + l31, 64);
    const float szB = __shfl(pBz, st * 32 + l31, 64);
    union {
      half8 v;
      f16x2 p[4];
    } xv;
    half8 z = {};
    xv.p[0] = __builtin_amdgcn_cvt_pkrtz((sxA - cAx) * 5.0f,
                                         (syA - cAy) * 5.0f);
    xv.p[1] = __builtin_amdgcn_cvt_pkrtz((szA - cAz) * 5.0f, 1.0f);
    xv.p[2] = __builtin_amdgcn_cvt_pkrtz(0.0f, 0.0f);
    xv.p[3] = __builtin_amdgcn_cvt_pkrtz(0.0f, 0.0f);
    xaA[st][4] = (h5 == 0) ? xv.v : z;
    xv.p[0] = __builtin_amdgcn_cvt_pkrtz((sxB - cBx) * 5.0f,
                                         (syB - cBy) * 5.0f);
    xv.p[1] = __builtin_amdgcn_cvt_pkrtz((szB - cBz) * 5.0f, 1.0f);
    xaB[st][4] = (h5 == 0) ? xv.v : z;
  }

  // ---- L0 (swapped, K=80): shared W0 frags; A/B chains interleaved ----
  half8 xa1A[2][4], xa1B[2][4];
#pragma unroll
  for (int nt = 0; nt < 2; ++nt) {
    half8 w0f[5];
#pragma unroll
    for (int ks = 0; ks < 5; ++ks)
      w0f[ks] = *(const half8*)&wt0[(nt * 32 + l31) * 80 + ks * 16 + koff];
#pragma unroll
    for (int st = 0; st < 2; ++st) {
      floatx16 accA, accB;
#pragma unroll
      for (int i = 0; i < 16; ++i) {
        accA[i] = 0.0f;
        accB[i] = 0.0f;
      }
#pragma unroll
      for (int ks = 0; ks < 5; ++ks) {
        accA = __builtin_amdgcn_mfma_f32_32x32x16_f16(w0f[ks], xaA[st][ks],
                                                      accA, 0, 0, 0);
        accB = __builtin_amdgcn_mfma_f32_32x32x16_f16(w0f[ks], xaB[st][ks],
                                                      accB, 0, 0, 0);
      }
      build_frags(accA, xa1A[st][2 * nt], xa1A[st][2 * nt + 1]);
      build_frags(accB, xa1B[st][2 * nt], xa1B[st][2 * nt + 1]);
    }
  }

  // ---- L1 (swapped, K=80: t1 via bias channel; shared W1 frags) ----
  half8 h1aA[2][4], h1aB[2][4];
#pragma unroll
  for (int nt = 0; nt < 2; ++nt) {
    half8 w1f[5];
#pragma unroll
    for (int ks = 0; ks < 5; ++ks)
      w1f[ks] = *(const half8*)&wt1q[(nt * 32 + l31) * 80 + ks * 16 + koff];
#pragma unroll
    for (int st = 0; st < 2; ++st) {
      floatx16 accA, accB;
#pragma unroll
      for (int i = 0; i < 16; ++i) {
        accA[i] = 0.0f;
        accB[i] = 0.0f;
      }
#pragma unroll
      for (int ks = 0; ks < 4; ++ks) {
        accA = __builtin_amdgcn_mfma_f32_32x32x16_f16(w1f[ks], xa1A[st][ks],
                                                      accA, 0, 0, 0);
        accB = __builtin_amdgcn_mfma_f32_32x32x16_f16(w1f[ks], xa1B[st][ks],
                                                      accB, 0, 0, 0);
      }
      accA = __builtin_amdgcn_mfma_f32_32x32x16_f16(w1f[4], bias_f, accA,
                                                    0, 0, 0);
      accB = __builtin_amdgcn_mfma_f32_32x32x16_f16(w1f[4], bias_f, accB,
                                                    0, 0, 0);
      build_frags(accA, h1aA[st][2 * nt], h1aA[st][2 * nt + 1]);
      build_frags(accB, h1aB[st][2 * nt], h1aB[st][2 * nt + 1]);
    }
  }

  // ---- L2 (unswapped): shared W2 frags; 4 indep chains per ct; maxpool ----
#pragma unroll
  for (int ct = 0; ct < 4; ++ct) {
    half8 b2c[4];
#pragma unroll
    for (int ks = 0; ks < 4; ++ks)
      b2c[ks] =
          *(const half8*)&wt2q[(ct * 32 + l31) * 64 + ks * 16 + koff];
    floatx16 aA0, aA1, aB0, aB1;
#pragma unroll
    for (int i = 0; i < 16; ++i) {
      aA0[i] = 0.0f;
      aA1[i] = 0.0f;
      aB0[i] = 0.0f;
      aB1[i] = 0.0f;
    }
#pragma unroll
    for (int ks = 0; ks < 4; ++ks) {
      aA0 = __builtin_amdgcn_mfma_f32_32x32x16_f16(h1aA[0][ks], b2c[ks], aA0,
                                                   0, 0, 0);
      aA1 = __builtin_amdgcn_mfma_f32_32x32x16_f16(h1aA[1][ks], b2c[ks], aA1,
                                                   0, 0, 0);
      aB0 = __builtin_amdgcn_mfma_f32_32x32x16_f16(h1aB[0][ks], b2c[ks], aB0,
                                                   0, 0, 0);
      aB1 = __builtin_amdgcn_mfma_f32_32x32x16_f16(h1aB[1][ks], b2c[ks], aB1,
                                                   0, 0, 0);
    }
    float mA = fmaxf(aA0[0], aA1[0]);
    float mB = fmaxf(aB0[0], aB1[0]);
#pragma unroll
    for (int i = 1; i < 16; ++i) {
      mA = fmaxf(mA, fmaxf(aA0[i], aA1[i]));
      mB = fmaxf(mB, fmaxf(aB0[i], aB1[i]));
    }
    float vA = fmaxf(mA + t2v[ct], 0.0f);  // relu(max+t) == max(relu(+t))
    float vB = fmaxf(mB + t2v[ct], 0.0f);
    vA = fmaxf(vA, __shfl_xor(vA, 32, 64));  // merge complementary halves
    vB = fmaxf(vB, __shfl_xor(vB, 32, 64));
    if (l < 32) {
      out[OFF_FEAT + (size_t)q0 * 128 + ct * 32 + l] = vA;
      out[OFF_FEAT + (size_t)q1 * 128 + ct * 32 + l] = vB;
    }
  }
}

// ---------------------------------------------------------------------------
// Fallback (ws too small): R18's proven mlp_r (LDS weights, reg hoist).
// ---------------------------------------------------------------------------
__global__ __launch_bounds__(128, 2) void mlp_r(
    const float* __restrict__ xyz, const float* __restrict__ features,
    const int* __restrict__ inds,
    const float* __restrict__ w0, const float* __restrict__ s0,
    const float* __restrict__ t0, const float* __restrict__ w1,
    const float* __restrict__ s1, const float* __restrict__ t1,
    const float* __restrict__ w2, const float* __restrict__ s2,
    const float* __restrict__ t2, float* __restrict__ out) {
  __shared__ _Float16 sm[SM_H];
  const int tid = threadIdx.x;
  const int w = tid >> 6;
  const int l = tid & 63;
  const int l31 = l & 31;
  const int h5 = l >> 5;
  const int koff = h5 * 8;

  {
    const int d = tid >> 1, hf = tid & 1;
    const float sd0 = s0[d], td0 = t0[d], sd1 = s1[d], td1 = t1[d];
#pragma unroll
    for (int j = 0; j < 44; ++j) {
      const int c = hf * 44 + j;
      float v = 0.0f;
      if (c < 64) v = w0[(3 + c) * 64 + d] * sd0;
      else if (c < 67) v = w0[(c - 64) * 64 + d] * sd0;
      else if (c == 67) v = td0;
      sm[WT0_S + d * P0 + c] = (_Float16)v;
      float v1 = 0.0f;
      if (c < 64) v1 = w1[c * 64 + d] * sd1;
      else if (c == 67) v1 = td1;
      sm[WT1_S + d * P0 + c] = (_Float16)v1;
    }
    const int ch = tid;
    const float sch = s2[ch];
#pragma unroll
    for (int c = 0; c < 64; ++c)
      sm[WT2_S + ch * P1 + c] = (_Float16)(w2[c * 128 + ch] * sch);
  }
  __syncthreads();

  half8 b0f[2][5], b1f[2][5], b2f[4][4];
#pragma unroll
  for (int nt = 0; nt < 2; ++nt)
#pragma unroll
    for (int ks = 0; ks < 5; ++ks) {
      b0f[nt][ks] =
          *(const half8*)&sm[WT0_S + (nt * 32 + l31) * P0 + ks * 16 + koff];
      b1f[nt][ks] =
          *(const half8*)&sm[WT1_S + (nt * 32 + l31) * P0 + ks * 16 + koff];
    }
#pragma unroll
  for (int ct = 0; ct < 4; ++ct)
#pragma unroll
    for (int ks = 0; ks < 4; ++ks)
      b2f[ct][ks] =
          *(const half8*)&sm[WT2_S + (ct * 32 + l31) * P1 + ks * 16 + koff];
  float t2v[4];
#pragma unroll
  for (int ct = 0; ct < 4; ++ct) t2v[ct] = t2[ct * 32 + l31];
  __syncthreads();

  half8 bias_f = {};
  if (h5 == 0) bias_f[3] = (_Float16)1.0f;

  _Float16* xbuf = sm + w * XSL;
  {
    half8 z = {};
    *(half8*)&xbuf[l * P0 + 72] = z;
  }

  const int lb = (blockIdx.x & 7) * ((int)gridDim.x >> 3) + (blockIdx.x >> 3);
  const int wq0 = (lb * 2 + w) * QPW;
  const int b = wq0 >> 11;
  const float* xb = xyz + (size_t)b * NN * 3;
  const float* fbase = features + (size_t)b * NN * CIN;

  int myidx = (int)out[OFF_IDX + (size_t)wq0 * NSAMPLE + l];
  int indv = inds[wq0];
  float cx = xb[indv * 3 + 0], cy = xb[indv * 3 + 1], cz = xb[indv * 3 + 2];
  float ppx = xb[myidx * 3 + 0], ppy = xb[myidx * 3 + 1],
        ppz = xb[myidx * 3 + 2];

#pragma unroll 1
  for (int qi = 0; qi < QPW; ++qi) {
    const int q = wq0 + qi;
    const int nq = (qi + 1 < QPW) ? q + 1 : q;

    float4 g[16];
#pragma unroll
    for (int i = 0; i < 16; ++i) {
      const int s = (l >> 2) + 16 * (i & 3);
      const int c = (l & 3) + 4 * (i >> 2);
      const int sidx = __shfl(myidx, s, 64);
      g[i] = *(const float4*)(fbase + (size_t)sidx * CIN + 4 * c);
    }
    const float fni = out[OFF_IDX + (size_t)nq * NSAMPLE + l];
    const int nindv = inds[nq];

#pragma unroll
    for (int i = 0; i < 16; ++i) {
      const int s = (l >> 2) + 16 * (i & 3);
      const int c = (l & 3) + 4 * (i >> 2);
      union {
        half4 v;
        f16x2 p[2];
      } hv;
      hv.p[0] = __builtin_amdgcn_cvt_pkrtz(g[i].x, g[i].y);
      hv.p[1] = __builtin_amdgcn_cvt_pkrtz(g[i].z, g[i].w);
      *(half4*)&xbuf[s * P0 + 4 * c] = hv.v;
    }
    {
      union {
        half8 v;
        f16x2 p[4];
      } xv;
      xv.p[0] =
          __builtin_amdgcn_cvt_pkrtz((ppx - cx) * 5.0f, (ppy - cy) * 5.0f);
      xv.p[1] = __builtin_amdgcn_cvt_pkrtz((ppz - cz) * 5.0f, 1.0f);
      xv.p[2] = __builtin_amdgcn_cvt_pkrtz(0.0f, 0.0f);
      xv.p[3] = __builtin_amdgcn_cvt_pkrtz(0.0f, 0.0f);
      *(half8*)&xbuf[l * P0 + 64] = xv.v;
    }

    half8 xa1[2][4];
    {
      half8 xa[2][5];
#pragma unroll
      for (int st = 0; st < 2; ++st)
#pragma unroll
        for (int ks = 0; ks < 5; ++ks)
          xa[st][ks] =
              *(const half8*)&xbuf[(st * 32 + l31) * P0 + ks * 16 + koff];
#pragma unroll
      for (int nt = 0; nt < 2; ++nt)
#pragma unroll
        for (int st = 0; st < 2; ++st) {
          floatx16 acc;
#pragma unroll
          for (int i = 0; i < 16; ++i) acc[i] = 0.0f;
#pragma unroll
          for (int ks = 0; ks < 5; ++ks)
            acc = __builtin_amdgcn_mfma_f32_32x32x16_f16(b0f[nt][ks],
                                                         xa[st][ks], acc,
                                                         0, 0, 0);
          build_frags(acc, xa1[st][2 * nt], xa1[st][2 * nt + 1]);
        }
    }

    const int nidxs = (int)fni;
    const float ncx = xb[nindv * 3 + 0];
    const float ncy = xb[nindv * 3 + 1];
    const float ncz = xb[nindv * 3 + 2];
    const float nppx = xb[nidxs * 3 + 0];
    const float nppy = xb[nidxs * 3 + 1];
    const float nppz = xb[nidxs * 3 + 2];

    half8 h1a[2][4];
    {
#pragma unroll
      for (int nt = 0; nt < 2; ++nt)
#pragma unroll
        for (int st = 0; st < 2; ++st) {
          floatx16 acc;
#pragma unroll
          for (int i = 0; i < 16; ++i) acc[i] = 0.0f;
#pragma unroll
          for (int ks = 0; ks < 4; ++ks)
            acc = __builtin_amdgcn_mfma_f32_32x32x16_f16(b1f[nt][ks],
                                                         xa1[st][ks], acc,
                                                         0, 0, 0);
          acc = __builtin_amdgcn_mfma_f32_32x32x16_f16(b1f[nt][4], bias_f,
                                                       acc, 0, 0, 0);
          build_frags(acc, h1a[st][2 * nt], h1a[st][2 * nt + 1]);
        }
    }

    {
#pragma unroll
      for (int ct = 0; ct < 4; ++ct) {
        floatx16 aA, aB;
#pragma unroll
        for (int i = 0; i < 16; ++i) {
          aA[i] = 0.0f;
          aB[i] = 0.0f;
        }
#pragma unroll
        for (int ks = 0; ks < 4; ++ks) {
          aA = __builtin_amdgcn_mfma_f32_32x32x16_f16(h1a[0][ks], b2f[ct][ks],
                                                      aA, 0, 0, 0);
          aB = __builtin_amdgcn_mfma_f32_32x32x16_f16(h1a[1][ks], b2f[ct][ks],
                                                      aB, 0, 0, 0);
        }
        float m = fmaxf(aA[0], aB[0]);
#pragma unroll
        for (int i = 1; i < 16; ++i) m = fmaxf(m, fmaxf(aA[i], aB[i]));
        float v = fmaxf(m + t2v[ct], 0.0f);
        v = fmaxf(v, __shfl_xor(v, 32, 64));
        if (l < 32) out[OFF_FEAT + (size_t)q * 128 + ct * 32 + l] = v;
      }
    }

    myidx = nidxs;
    cx = ncx; cy = ncy; cz = ncz;
    ppx = nppx; ppy = nppy; ppz = nppz;
  }
}

extern "C" void kernel_launch(void* const* d_in, const int* in_sizes, int n_in,
                              void* d_out, int out_size, void* d_ws,
                              size_t ws_size, hipStream_t stream) {
  const float* xyz = (const float*)d_in[0];
  const float* features = (const float*)d_in[1];
  const int* inds = (const int*)d_in[2];
  const float* w0 = (const float*)d_in[3];
  const float* s0 = (const float*)d_in[4];
  const float* t0 = (const float*)d_in[5];
  const float* w1 = (const float*)d_in[6];
  const float* s1 = (const float*)d_in[7];
  const float* t1 = (const float*)d_in[8];
  const float* w2 = (const float*)d_in[9];
  const float* s2 = (const float*)d_in[10];
  const float* t2 = (const float*)d_in[11];
  float* out = (float*)d_out;

  _Float16* ws16 = (ws_size >= WS_NEED) ? (_Float16*)d_ws : nullptr;

  const int nquery = BB * NPOINT;  // 16384
  // ballq: 4 queries/wave, 4 waves/block -> 1024 blocks
  ballq_kernel<<<nquery / 16, 256, 0, stream>>>(
      xyz, inds, out, features, ws16, w0, s0, t0, w1, s1, t1, w2, s2);
  if (ws16) {
    // paired-chain: one wave per block, both queries in flight -> 8192 blocks
    mlp_p<<<nquery / 2, 64, 0, stream>>>(xyz, ws16, inds, t2, out);
  } else {
    mlp_r<<<nquery / (2 * QPW), 128, 0, stream>>>(
        xyz, features, inds, w0, s0, t0, w1, s1, t1, w2, s2, t2, out);
  }
}

// Round 12
// 168.407 us; speedup vs baseline: 1.1260x; 1.1260x over previous
//
#include <hip/hip_runtime.h>

#define BB 8
#define NN 8192
#define NPOINT 2048
#define NSAMPLE 64
#define CIN 64
#define RADIUS 0.2f
#define R2 (RADIUS * RADIUS)

// d_out layout (flat floats, reference return order)
#define OFF_NEWXYZ 0
#define OFF_FEAT (BB * NPOINT * 3)
#define OFF_INDS (OFF_FEAT + BB * NPOINT * 128)
#define OFF_IDX (OFF_INDS + BB * NPOINT)

typedef _Float16 half8 __attribute__((ext_vector_type(8)));
typedef _Float16 half4 __attribute__((ext_vector_type(4)));
typedef __fp16 f16x2 __attribute__((ext_vector_type(2)));
typedef float floatx16 __attribute__((ext_vector_type(16)));
typedef unsigned int uint2v __attribute__((ext_vector_type(2)));

// Fallback-kernel LDS strides (halves).
#define P0 88
#define P1 72
#define WT0_S 0
#define WT1_S (64 * P0)
#define WT2_S (WT1_S + 64 * P0)
#define SM_H (WT2_S + 128 * P1)   // 40960 B (fallback mlp_r)
#define XSL (64 * P0)

#define QPW 8  // fallback queries/wave

// d_ws layout (halves): fp16 features, then fp16 weight fragment tables.
// W0: 64x80 (cols 0-63 feat, 64-66 xyz, 67 bias=t0). W1: 64x80 (col 67 =
// t1 bias). W2: 128x64.
#define WSF16H (BB * NN * CIN)
#define WT0_OFF WSF16H
#define WT1_OFF (WT0_OFF + 64 * 80)
#define WT2_OFF (WT1_OFF + 64 * 80)
#define WS_END (WT2_OFF + 128 * 64)
#define WS_NEED ((size_t)WS_END * 2)

// ---------------------------------------------------------------------------
// Kernel 1 (R20 config + R23 per-query skip): ball query, TWO queries per
// wave at full 32-waves/CU residency (R22 lesson: 4q/wave halves residency
// and deepens the max-of-N early-exit — regression). Once a chain fills
// (cntX >= NSAMPLE, wave-uniform), its dot/ballot/scatter work is skipped —
// bit-identical results, saves the asymmetric-fill tail. Prologue jobs:
// fp32->fp16 feature conversion + block-0 weight fragment tables (proven).
// ---------------------------------------------------------------------------
__global__ __launch_bounds__(256) void ballq_kernel(
    const float* __restrict__ xyz, const int* __restrict__ inds,
    float* __restrict__ out, const float* __restrict__ features,
    _Float16* __restrict__ ws16, const float* __restrict__ w0,
    const float* __restrict__ s0, const float* __restrict__ t0,
    const float* __restrict__ w1, const float* __restrict__ s1,
    const float* __restrict__ t1, const float* __restrict__ w2,
    const float* __restrict__ s2) {
  if (ws16) {
    // feature conversion: 2048 blocks x 256 thr x 2 float4 = exact fit
    const int t = blockIdx.x * 256 + threadIdx.x;
    const float4* src = (const float4*)features;
    const float4 a = src[2 * t + 0];
    const float4 b = src[2 * t + 1];
    union {
      half8 v;
      f16x2 p[4];
    } u;
    u.p[0] = __builtin_amdgcn_cvt_pkrtz(a.x, a.y);
    u.p[1] = __builtin_amdgcn_cvt_pkrtz(a.z, a.w);
    u.p[2] = __builtin_amdgcn_cvt_pkrtz(b.x, b.y);
    u.p[3] = __builtin_amdgcn_cvt_pkrtz(b.z, b.w);
    ((half8*)ws16)[t] = u.v;
    if (blockIdx.x == 0) {
      const int tt = threadIdx.x;
      if (tt < 64) {
        const int d = tt;
        const float sd = s0[d], td = t0[d];
        _Float16* row = ws16 + WT0_OFF + d * 80;
        for (int c = 0; c < 80; ++c) {
          float v = 0.0f;
          if (c < 64) v = w0[(3 + c) * 64 + d] * sd;
          else if (c < 67) v = w0[(c - 64) * 64 + d] * sd;
          else if (c == 67) v = td;
          row[c] = (_Float16)v;
        }
      } else if (tt < 128) {
        const int d = tt - 64;
        const float sd = s1[d], td = t1[d];
        _Float16* row = ws16 + WT1_OFF + d * 80;
        for (int c = 0; c < 80; ++c) {
          float v = 0.0f;
          if (c < 64) v = w1[c * 64 + d] * sd;
          else if (c == 67) v = td;
          row[c] = (_Float16)v;
        }
      } else {
        const int d2 = tt - 128;
        const float sd = s2[d2];
        _Float16* row = ws16 + WT2_OFF + d2 * 64;
        for (int c = 0; c < 64; ++c) row[c] = (_Float16)(w2[c * 128 + d2] * sd);
      }
    }
  }

  __shared__ int sidx[4][2][NSAMPLE];  // 2 KB: 4 waves x 2 queries
  const int wave = (blockIdx.x * 256 + threadIdx.x) >> 6;
  const int lane = threadIdx.x & 63;
  const int wid = threadIdx.x >> 6;
  const int q0 = wave * 2, q1 = q0 + 1;
  const int b = q0 >> 11;  // NPOINT = 2048; pair shares batch

  const float* xb = xyz + (size_t)b * NN * 3;
  const int i0 = inds[q0], i1 = inds[q1];
  const float c0x = xb[i0 * 3 + 0], c0y = xb[i0 * 3 + 1], c0z = xb[i0 * 3 + 2];
  const float c1x = xb[i1 * 3 + 0], c1y = xb[i1 * 3 + 1], c1z = xb[i1 * 3 + 2];

  if (lane < 2) {
    const int qq_ = lane ? q1 : q0;
    const int ii = lane ? i1 : i0;
    out[OFF_NEWXYZ + (size_t)qq_ * 3 + 0] = lane ? c1x : c0x;
    out[OFF_NEWXYZ + (size_t)qq_ * 3 + 1] = lane ? c1y : c0y;
    out[OFF_NEWXYZ + (size_t)qq_ * 3 + 2] = lane ? c1z : c0z;
    out[OFF_INDS + qq_] = (float)ii;
  }

  const float qq0 = c0x * c0x + c0y * c0y + c0z * c0z;
  const float qq1 = c1x * c1x + c1y * c1y + c1z * c1z;

  int cnt0 = 0, cnt1 = 0;
  float ax[4], ay[4], az[4];
#pragma unroll
  for (int k = 0; k < 4; ++k) {
    const float* p = xb + (size_t)(k * 64 + lane) * 3;
    ax[k] = p[0];
    ay[k] = p[1];
    az[k] = p[2];
  }
  for (int j0 = 0; j0 < NN; j0 += 256) {
    float bx[4] = {0}, by[4] = {0}, bz[4] = {0};
    const int jn = j0 + 256;
    if (jn < NN) {  // prefetch next chunk while ballots run on current
#pragma unroll
      for (int k = 0; k < 4; ++k) {
        const float* p = xb + (size_t)(jn + k * 64 + lane) * 3;
        bx[k] = p[0];
        by[k] = p[1];
        bz[k] = p[2];
      }
    }
    // wave-uniform per-query skip: once a chain fills, its work vanishes
    // (bit-identical: pos >= NSAMPLE writes were discarded anyway).
    if (cnt0 < NSAMPLE) {
#pragma unroll
      for (int k = 0; k < 4; ++k) {  // k-major preserves point order
        const int j = j0 + k * 64 + lane;
        const float nn_ = ax[k] * ax[k] + ay[k] * ay[k] + az[k] * az[k];
        const float dot0 = c0x * ax[k] + c0y * ay[k] + c0z * az[k];
        const bool hit0 = (qq0 + nn_ - 2.0f * dot0) < R2;
        const unsigned long long m0 = __ballot(hit0);
        if (hit0) {
          const int pos = cnt0 + (int)__popcll(m0 & ((1ull << lane) - 1ull));
          if (pos < NSAMPLE) sidx[wid][0][pos] = j;
        }
        cnt0 += (int)__popcll(m0);
      }
    }
    if (cnt1 < NSAMPLE) {
#pragma unroll
      for (int k = 0; k < 4; ++k) {
        const int j = j0 + k * 64 + lane;
        const float nn_ = ax[k] * ax[k] + ay[k] * ay[k] + az[k] * az[k];
        const float dot1 = c1x * ax[k] + c1y * ay[k] + c1z * az[k];
        const bool hit1 = (qq1 + nn_ - 2.0f * dot1) < R2;
        const unsigned long long m1 = __ballot(hit1);
        if (hit1) {
          const int pos = cnt1 + (int)__popcll(m1 & ((1ull << lane) - 1ull));
          if (pos < NSAMPLE) sidx[wid][1][pos] = j;
        }
        cnt1 += (int)__popcll(m1);
      }
    }
    if (cnt0 >= NSAMPLE && cnt1 >= NSAMPLE) break;
#pragma unroll
    for (int k = 0; k < 4; ++k) {
      ax[k] = bx[k];
      ay[k] = by[k];
      az[k] = bz[k];
    }
  }
  // Pad with first hit (center always hits itself -> cnt >= 1). Same-wave DS
  // ops are in-order: reads below see the scatter writes without a barrier.
  const int v0 = sidx[wid][0][lane < cnt0 ? lane : 0];
  out[OFF_IDX + (size_t)q0 * NSAMPLE + lane] = (float)v0;
  const int v1 = sidx[wid][1][lane < cnt1 ? lane : 0];
  out[OFF_IDX + (size_t)q1 * NSAMPLE + lane] = (float)v1;
}

// ---- in-register layer boundary (R16/R18-verified) --------------------------
__device__ inline unsigned int pkru(float a, float b) {
  union {
    f16x2 p;
    unsigned int u;
  } t;
  t.p = __builtin_amdgcn_cvt_pkrtz(fmaxf(a, 0.0f), fmaxf(b, 0.0f));
  return t.u;
}
__device__ inline void build_frags(const floatx16& acc, half8& f0, half8& f1) {
  unsigned int P[4], Q[4];
#pragma unroll
  for (int rg = 0; rg < 4; ++rg) {
    P[rg] = pkru(acc[4 * rg + 0], acc[4 * rg + 1]);
    Q[rg] = pkru(acc[4 * rg + 2], acc[4 * rg + 3]);
  }
  union {
    unsigned int u[4];
    half8 h;
  } o;
  uint2v sp = __builtin_amdgcn_permlane32_swap(P[0], P[1], false, false);
  uint2v sq = __builtin_amdgcn_permlane32_swap(Q[0], Q[1], false, false);
  o.u[0] = sp.x; o.u[1] = sq.x; o.u[2] = sp.y; o.u[3] = sq.y;
  f0 = o.h;
  sp = __builtin_amdgcn_permlane32_swap(P[2], P[3], false, false);
  sq = __builtin_amdgcn_permlane32_swap(Q[2], Q[3], false, false);
  o.u[0] = sp.x; o.u[1] = sq.x; o.u[2] = sp.y; o.u[3] = sq.y;
  f1 = o.h;
}

// ---------------------------------------------------------------------------
// Kernel 2 (R20-proven, 57-62us): PAIRED-CHAIN zero-LDS MLP. Both queries run
// simultaneously (two independent dep chains interleave; shared weight
// fragments). Zero LDS; 8192 one-wave blocks; (64,2). UNCHANGED.
// ---------------------------------------------------------------------------
__global__ __launch_bounds__(64, 2) void mlp_p(
    const float* __restrict__ xyz, const _Float16* __restrict__ ws16,
    const int* __restrict__ inds, const float* __restrict__ t2,
    float* __restrict__ out) {
  const int l = threadIdx.x & 63;
  const int l31 = l & 31;
  const int h5 = l >> 5;
  const int koff = h5 * 8;

  // XCD swizzle: 8192 blocks = 8 XCDs x 1024; 1024 logical blocks = 1 batch.
  const int lb = (blockIdx.x & 7) * ((int)gridDim.x >> 3) + (blockIdx.x >> 3);
  const int q0 = lb * 2, q1 = q0 + 1;  // pair never straddles batch boundary
  const int b = q0 >> 11;
  const float* xb = xyz + (size_t)b * NN * 3;
  const _Float16* fb16 = ws16 + (size_t)b * NN * CIN;
  const _Float16* wt0 = ws16 + WT0_OFF;
  const _Float16* wt1q = wt0 + 64 * 80;
  const _Float16* wt2q = wt0 + 64 * 80 + 64 * 80;

  float t2v[4];
#pragma unroll
  for (int ct = 0; ct < 4; ++ct) t2v[ct] = t2[ct * 32 + l31];
  // constant K=80 bias fragment for L1 (k = 64 + 8*h5 + j; k==67 -> 1.0)
  half8 bias_f = {};
  if (h5 == 0) bias_f[3] = (_Float16)1.0f;

  // ---- prologue: BOTH queries' idx / center / pp (all issued up front) ----
  const int idxA = (int)out[OFF_IDX + (size_t)q0 * NSAMPLE + l];
  const int idxB = (int)out[OFF_IDX + (size_t)q1 * NSAMPLE + l];
  const int iA = inds[q0], iB = inds[q1];
  const float cAx = xb[iA * 3 + 0], cAy = xb[iA * 3 + 1], cAz = xb[iA * 3 + 2];
  const float cBx = xb[iB * 3 + 0], cBy = xb[iB * 3 + 1], cBz = xb[iB * 3 + 2];
  const float pAx = xb[idxA * 3 + 0], pAy = xb[idxA * 3 + 1],
              pAz = xb[idxA * 3 + 2];
  const float pBx = xb[idxB * 3 + 0], pBy = xb[idxB * 3 + 1],
              pBz = xb[idxB * 3 + 2];

  // ---- fragment-direct fp16 gathers for BOTH queries (32 loads in flight) --
  half8 xaA[2][5], xaB[2][5];
#pragma unroll
  for (int st = 0; st < 2; ++st) {
    const int sA = __shfl(idxA, st * 32 + l31, 64);
    const int sB = __shfl(idxB, st * 32 + l31, 64);
    const _Float16* baseA = fb16 + (size_t)sA * CIN + koff;
    const _Float16* baseB = fb16 + (size_t)sB * CIN + koff;
#pragma unroll
    for (int ks = 0; ks < 4; ++ks) {
      xaA[st][ks] = *(const half8*)(baseA + ks * 16);
      xaB[st][ks] = *(const half8*)(baseB + ks * 16);
    }
  }
  // xyz+bias fragments (k 64..79): h5==0 holds {dx,dy,dz,1,0..}, h5==1 zeros
#pragma unroll
  for (int st = 0; st < 2; ++st) {
    const float sxA = __shfl(pAx, st * 32 + l31, 64);
    const float syA = __shfl(pAy, st * 32 + l31, 64);
    const float szA = __shfl(pAz, st * 32 + l31, 64);
    const float sxB = __shfl(pBx, st * 32 + l31, 64);
    const float syB = __shfl(pBy, st * 32 + l31, 64);
    const float szB = __shfl(pBz, st * 32 + l31, 64);
    union {
      half8 v;
      f16x2 p[4];
    } xv;
    half8 z = {};
    xv.p[0] = __builtin_amdgcn_cvt_pkrtz((sxA - cAx) * 5.0f,
                                         (syA - cAy) * 5.0f);
    xv.p[1] = __builtin_amdgcn_cvt_pkrtz((szA - cAz) * 5.0f, 1.0f);
    xv.p[2] = __builtin_amdgcn_cvt_pkrtz(0.0f, 0.0f);
    xv.p[3] = __builtin_amdgcn_cvt_pkrtz(0.0f, 0.0f);
    xaA[st][4] = (h5 == 0) ? xv.v : z;
    xv.p[0] = __builtin_amdgcn_cvt_pkrtz((sxB - cBx) * 5.0f,
                                         (syB - cBy) * 5.0f);
    xv.p[1] = __builtin_amdgcn_cvt_pkrtz((szB - cBz) * 5.0f, 1.0f);
    xaB[st][4] = (h5 == 0) ? xv.v : z;
  }

  // ---- L0 (swapped, K=80): shared W0 frags; A/B chains interleaved ----
  half8 xa1A[2][4], xa1B[2][4];
#pragma unroll
  for (int nt = 0; nt < 2; ++nt) {
    half8 w0f[5];
#pragma unroll
    for (int ks = 0; ks < 5; ++ks)
      w0f[ks] = *(const half8*)&wt0[(nt * 32 + l31) * 80 + ks * 16 + koff];
#pragma unroll
    for (int st = 0; st < 2; ++st) {
      floatx16 accA, accB;
#pragma unroll
      for (int i = 0; i < 16; ++i) {
        accA[i] = 0.0f;
        accB[i] = 0.0f;
      }
#pragma unroll
      for (int ks = 0; ks < 5; ++ks) {
        accA = __builtin_amdgcn_mfma_f32_32x32x16_f16(w0f[ks], xaA[st][ks],
                                                      accA, 0, 0, 0);
        accB = __builtin_amdgcn_mfma_f32_32x32x16_f16(w0f[ks], xaB[st][ks],
                                                      accB, 0, 0, 0);
      }
      build_frags(accA, xa1A[st][2 * nt], xa1A[st][2 * nt + 1]);
      build_frags(accB, xa1B[st][2 * nt], xa1B[st][2 * nt + 1]);
    }
  }

  // ---- L1 (swapped, K=80: t1 via bias channel; shared W1 frags) ----
  half8 h1aA[2][4], h1aB[2][4];
#pragma unroll
  for (int nt = 0; nt < 2; ++nt) {
    half8 w1f[5];
#pragma unroll
    for (int ks = 0; ks < 5; ++ks)
      w1f[ks] = *(const half8*)&wt1q[(nt * 32 + l31) * 80 + ks * 16 + koff];
#pragma unroll
    for (int st = 0; st < 2; ++st) {
      floatx16 accA, accB;
#pragma unroll
      for (int i = 0; i < 16; ++i) {
        accA[i] = 0.0f;
        accB[i] = 0.0f;
      }
#pragma unroll
      for (int ks = 0; ks < 4; ++ks) {
        accA = __builtin_amdgcn_mfma_f32_32x32x16_f16(w1f[ks], xa1A[st][ks],
                                                      accA, 0, 0, 0);
        accB = __builtin_amdgcn_mfma_f32_32x32x16_f16(w1f[ks], xa1B[st][ks],
                                                      accB, 0, 0, 0);
      }
      accA = __builtin_amdgcn_mfma_f32_32x32x16_f16(w1f[4], bias_f, accA,
                                                    0, 0, 0);
      accB = __builtin_amdgcn_mfma_f32_32x32x16_f16(w1f[4], bias_f, accB,
                                                    0, 0, 0);
      build_frags(accA, h1aA[st][2 * nt], h1aA[st][2 * nt + 1]);
      build_frags(accB, h1aB[st][2 * nt], h1aB[st][2 * nt + 1]);
    }
  }

  // ---- L2 (unswapped): shared W2 frags; 4 indep chains per ct; maxpool ----
#pragma unroll
  for (int ct = 0; ct < 4; ++ct) {
    half8 b2c[4];
#pragma unroll
    for (int ks = 0; ks < 4; ++ks)
      b2c[ks] =
          *(const half8*)&wt2q[(ct * 32 + l31) * 64 + ks * 16 + koff];
    floatx16 aA0, aA1, aB0, aB1;
#pragma unroll
    for (int i = 0; i < 16; ++i) {
      aA0[i] = 0.0f;
      aA1[i] = 0.0f;
      aB0[i] = 0.0f;
      aB1[i] = 0.0f;
    }
#pragma unroll
    for (int ks = 0; ks < 4; ++ks) {
      aA0 = __builtin_amdgcn_mfma_f32_32x32x16_f16(h1aA[0][ks], b2c[ks], aA0,
                                                   0, 0, 0);
      aA1 = __builtin_amdgcn_mfma_f32_32x32x16_f16(h1aA[1][ks], b2c[ks], aA1,
                                                   0, 0, 0);
      aB0 = __builtin_amdgcn_mfma_f32_32x32x16_f16(h1aB[0][ks], b2c[ks], aB0,
                                                   0, 0, 0);
      aB1 = __builtin_amdgcn_mfma_f32_32x32x16_f16(h1aB[1][ks], b2c[ks], aB1,
                                                   0, 0, 0);
    }
    float mA = fmaxf(aA0[0], aA1[0]);
    float mB = fmaxf(aB0[0], aB1[0]);
#pragma unroll
    for (int i = 1; i < 16; ++i) {
      mA = fmaxf(mA, fmaxf(aA0[i], aA1[i]));
      mB = fmaxf(mB, fmaxf(aB0[i], aB1[i]));
    }
    float vA = fmaxf(mA + t2v[ct], 0.0f);  // relu(max+t) == max(relu(+t))
    float vB = fmaxf(mB + t2v[ct], 0.0f);
    vA = fmaxf(vA, __shfl_xor(vA, 32, 64));  // merge complementary halves
    vB = fmaxf(vB, __shfl_xor(vB, 32, 64));
    if (l < 32) {
      out[OFF_FEAT + (size_t)q0 * 128 + ct * 32 + l] = vA;
      out[OFF_FEAT + (size_t)q1 * 128 + ct * 32 + l] = vB;
    }
  }
}

// ---------------------------------------------------------------------------
// Fallback (ws too small): R18's proven mlp_r (LDS weights, reg hoist).
// ---------------------------------------------------------------------------
__global__ __launch_bounds__(128, 2) void mlp_r(
    const float* __restrict__ xyz, const float* __restrict__ features,
    const int* __restrict__ inds,
    const float* __restrict__ w0, const float* __restrict__ s0,
    const float* __restrict__ t0, const float* __restrict__ w1,
    const float* __restrict__ s1, const float* __restrict__ t1,
    const float* __restrict__ w2, const float* __restrict__ s2,
    const float* __restrict__ t2, float* __restrict__ out) {
  __shared__ _Float16 sm[SM_H];
  const int tid = threadIdx.x;
  const int w = tid >> 6;
  const int l = tid & 63;
  const int l31 = l & 31;
  const int h5 = l >> 5;
  const int koff = h5 * 8;

  {
    const int d = tid >> 1, hf = tid & 1;
    const float sd0 = s0[d], td0 = t0[d], sd1 = s1[d], td1 = t1[d];
#pragma unroll
    for (int j = 0; j < 44; ++j) {
      const int c = hf * 44 + j;
      float v = 0.0f;
      if (c < 64) v = w0[(3 + c) * 64 + d] * sd0;
      else if (c < 67) v = w0[(c - 64) * 64 + d] * sd0;
      else if (c == 67) v = td0;
      sm[WT0_S + d * P0 + c] = (_Float16)v;
      float v1 = 0.0f;
      if (c < 64) v1 = w1[c * 64 + d] * sd1;
      else if (c == 67) v1 = td1;
      sm[WT1_S + d * P0 + c] = (_Float16)v1;
    }
    const int ch = tid;
    const float sch = s2[ch];
#pragma unroll
    for (int c = 0; c < 64; ++c)
      sm[WT2_S + ch * P1 + c] = (_Float16)(w2[c * 128 + ch] * sch);
  }
  __syncthreads();

  half8 b0f[2][5], b1f[2][5], b2f[4][4];
#pragma unroll
  for (int nt = 0; nt < 2; ++nt)
#pragma unroll
    for (int ks = 0; ks < 5; ++ks) {
      b0f[nt][ks] =
          *(const half8*)&sm[WT0_S + (nt * 32 + l31) * P0 + ks * 16 + koff];
      b1f[nt][ks] =
          *(const half8*)&sm[WT1_S + (nt * 32 + l31) * P0 + ks * 16 + koff];
    }
#pragma unroll
  for (int ct = 0; ct < 4; ++ct)
#pragma unroll
    for (int ks = 0; ks < 4; ++ks)
      b2f[ct][ks] =
          *(const half8*)&sm[WT2_S + (ct * 32 + l31) * P1 + ks * 16 + koff];
  float t2v[4];
#pragma unroll
  for (int ct = 0; ct < 4; ++ct) t2v[ct] = t2[ct * 32 + l31];
  __syncthreads();

  half8 bias_f = {};
  if (h5 == 0) bias_f[3] = (_Float16)1.0f;

  _Float16* xbuf = sm + w * XSL;
  {
    half8 z = {};
    *(half8*)&xbuf[l * P0 + 72] = z;
  }

  const int lb = (blockIdx.x & 7) * ((int)gridDim.x >> 3) + (blockIdx.x >> 3);
  const int wq0 = (lb * 2 + w) * QPW;
  const int b = wq0 >> 11;
  const float* xb = xyz + (size_t)b * NN * 3;
  const float* fbase = features + (size_t)b * NN * CIN;

  int myidx = (int)out[OFF_IDX + (size_t)wq0 * NSAMPLE + l];
  int indv = inds[wq0];
  float cx = xb[indv * 3 + 0], cy = xb[indv * 3 + 1], cz = xb[indv * 3 + 2];
  float ppx = xb[myidx * 3 + 0], ppy = xb[myidx * 3 + 1],
        ppz = xb[myidx * 3 + 2];

#pragma unroll 1
  for (int qi = 0; qi < QPW; ++qi) {
    const int q = wq0 + qi;
    const int nq = (qi + 1 < QPW) ? q + 1 : q;

    float4 g[16];
#pragma unroll
    for (int i = 0; i < 16; ++i) {
      const int s = (l >> 2) + 16 * (i & 3);
      const int c = (l & 3) + 4 * (i >> 2);
      const int sidx = __shfl(myidx, s, 64);
      g[i] = *(const float4*)(fbase + (size_t)sidx * CIN + 4 * c);
    }
    const float fni = out[OFF_IDX + (size_t)nq * NSAMPLE + l];
    const int nindv = inds[nq];

#pragma unroll
    for (int i = 0; i < 16; ++i) {
      const int s = (l >> 2) + 16 * (i & 3);
      const int c = (l & 3) + 4 * (i >> 2);
      union {
        half4 v;
        f16x2 p[2];
      } hv;
      hv.p[0] = __builtin_amdgcn_cvt_pkrtz(g[i].x, g[i].y);
      hv.p[1] = __builtin_amdgcn_cvt_pkrtz(g[i].z, g[i].w);
      *(half4*)&xbuf[s * P0 + 4 * c] = hv.v;
    }
    {
      union {
        half8 v;
        f16x2 p[4];
      } xv;
      xv.p[0] =
          __builtin_amdgcn_cvt_pkrtz((ppx - cx) * 5.0f, (ppy - cy) * 5.0f);
      xv.p[1] = __builtin_amdgcn_cvt_pkrtz((ppz - cz) * 5.0f, 1.0f);
      xv.p[2] = __builtin_amdgcn_cvt_pkrtz(0.0f, 0.0f);
      xv.p[3] = __builtin_amdgcn_cvt_pkrtz(0.0f, 0.0f);
      *(half8*)&xbuf[l * P0 + 64] = xv.v;
    }

    half8 xa1[2][4];
    {
      half8 xa[2][5];
#pragma unroll
      for (int st = 0; st < 2; ++st)
#pragma unroll
        for (int ks = 0; ks < 5; ++ks)
          xa[st][ks] =
              *(const half8*)&xbuf[(st * 32 + l31) * P0 + ks * 16 + koff];
#pragma unroll
      for (int nt = 0; nt < 2; ++nt)
#pragma unroll
        for (int st = 0; st < 2; ++st) {
          floatx16 acc;
#pragma unroll
          for (int i = 0; i < 16; ++i) acc[i] = 0.0f;
#pragma unroll
          for (int ks = 0; ks < 5; ++ks)
            acc = __builtin_amdgcn_mfma_f32_32x32x16_f16(b0f[nt][ks],
                                                         xa[st][ks], acc,
                                                         0, 0, 0);
          build_frags(acc, xa1[st][2 * nt], xa1[st][2 * nt + 1]);
        }
    }

    const int nidxs = (int)fni;
    const float ncx = xb[nindv * 3 + 0];
    const float ncy = xb[nindv * 3 + 1];
    const float ncz = xb[nindv * 3 + 2];
    const float nppx = xb[nidxs * 3 + 0];
    const float nppy = xb[nidxs * 3 + 1];
    const float nppz = xb[nidxs * 3 + 2];

    half8 h1a[2][4];
    {
#pragma unroll
      for (int nt = 0; nt < 2; ++nt)
#pragma unroll
        for (int st = 0; st < 2; ++st) {
          floatx16 acc;
#pragma unroll
          for (int i = 0; i < 16; ++i) acc[i] = 0.0f;
#pragma unroll
          for (int ks = 0; ks < 4; ++ks)
            acc = __builtin_amdgcn_mfma_f32_32x32x16_f16(b1f[nt][ks],
                                                         xa1[st][ks], acc,
                                                         0, 0, 0);
          acc = __builtin_amdgcn_mfma_f32_32x32x16_f16(b1f[nt][4], bias_f,
                                                       acc, 0, 0, 0);
          build_frags(acc, h1a[st][2 * nt], h1a[st][2 * nt + 1]);
        }
    }

    {
#pragma unroll
      for (int ct = 0; ct < 4; ++ct) {
        floatx16 aA, aB;
#pragma unroll
        for (int i = 0; i < 16; ++i) {
          aA[i] = 0.0f;
          aB[i] = 0.0f;
        }
#pragma unroll
        for (int ks = 0; ks < 4; ++ks) {
          aA = __builtin_amdgcn_mfma_f32_32x32x16_f16(h1a[0][ks], b2f[ct][ks],
                                                      aA, 0, 0, 0);
          aB = __builtin_amdgcn_mfma_f32_32x32x16_f16(h1a[1][ks], b2f[ct][ks],
                                                      aB, 0, 0, 0);
        }
        float m = fmaxf(aA[0], aB[0]);
#pragma unroll
        for (int i = 1; i < 16; ++i) m = fmaxf(m, fmaxf(aA[i], aB[i]));
        float v = fmaxf(m + t2v[ct], 0.0f);
        v = fmaxf(v, __shfl_xor(v, 32, 64));
        if (l < 32) out[OFF_FEAT + (size_t)q * 128 + ct * 32 + l] = v;
      }
    }

    myidx = nidxs;
    cx = ncx; cy = ncy; cz = ncz;
    ppx = nppx; ppy = nppy; ppz = nppz;
  }
}

extern "C" void kernel_launch(void* const* d_in, const int* in_sizes, int n_in,
                              void* d_out, int out_size, void* d_ws,
                              size_t ws_size, hipStream_t stream) {
  const float* xyz = (const float*)d_in[0];
  const float* features = (const float*)d_in[1];
  const int* inds = (const int*)d_in[2];
  const float* w0 = (const float*)d_in[3];
  const float* s0 = (const float*)d_in[4];
  const float* t0 = (const float*)d_in[5];
  const float* w1 = (const float*)d_in[6];
  const float* s1 = (const float*)d_in[7];
  const float* t1 = (const float*)d_in[8];
  const float* w2 = (const float*)d_in[9];
  const float* s2 = (const float*)d_in[10];
  const float* t2 = (const float*)d_in[11];
  float* out = (float*)d_out;

  _Float16* ws16 = (ws_size >= WS_NEED) ? (_Float16*)d_ws : nullptr;

  const int nquery = BB * NPOINT;  // 16384
  // ballq: 2 queries per wave -> 8192 waves -> 2048 blocks (full residency)
  ballq_kernel<<<nquery / 8, 256, 0, stream>>>(xyz, inds, out, features, ws16,
                                               w0, s0, t0, w1, s1, t1, w2, s2);
  if (ws16) {
    // paired-chain: one wave per block, both queries in flight -> 8192 blocks
    mlp_p<<<nquery / 2, 64, 0, stream>>>(xyz, ws16, inds, t2, out);
  } else {
    mlp_r<<<nquery / (2 * QPW), 128, 0, stream>>>(
        xyz, features, inds, w0, s0, t0, w1, s1, t1, w2, s2, t2, out);
  }
}